// Round 12
// baseline (118.785 us; speedup 1.0000x reference)
//
#include <hip/hip_runtime.h>
#include <math.h>

#define S_LEN 2048
#define NB    2
#define CQ_   256
#define CC_   256
#define DH    50
#define KW    101
#define PS    100
#define WTH   1e-5f // phase-C weight skip threshold

#define NB2   384   // padded B width: 256 V cols + 100 hidden + 28 zero
#define MT    64
#define NT    64
#define KC    32
#define HOFF  ((size_t)4096 * NB2)   // G half-offset (split-K)

// ---------------------------------------------------------------------------
// k_prep: BT[c][n] = n<256 ? Wa[c][n] : (n<356 ? Wp[n-256][c] : 0).
// (R9-verified; Wa untransposed: V[q] = sum_c ct[c]*Wa[c][q].)
// ---------------------------------------------------------------------------
__global__ __launch_bounds__(NB2) void k_prep(const float* __restrict__ Wa,
    const float* __restrict__ Wp, float* __restrict__ BT) {
  const int c = blockIdx.x, n = threadIdx.x;
  float v = 0.0f;
  if (n < CQ_)            v = Wa[(size_t)c * CQ_ + n];
  else if (n < CQ_ + PS)  v = Wp[(size_t)(n - CQ_) * CC_ + c];
  BT[(size_t)c * NB2 + n] = v;
}

// ---------------------------------------------------------------------------
// k_gemm: SPLIT-K=2 version of R9's verified 64x64 GEMM.
// R9's flaw wasn't the tile (it passed; ~38us) — it was 384 blocks = 1.5/CU:
// half the CUs serialized 2 blocks and barrier drains had no co-resident
// cover. 768 blocks = exactly 3/CU, balanced; other blocks' K-loops cover
// each block's barrier-exposed global latency. Halves written to G[0],G[1];
// consumers add them in registers (no reduce kernel).
// ---------------------------------------------------------------------------
__global__ __launch_bounds__(256, 3) void k_gemm(const float* __restrict__ ct,
    const float* __restrict__ BT, float* __restrict__ G) {
  const int x  = blockIdx.x;
  const int kh = (x >= 384) ? 1 : 0;
  const int t  = x - kh * 384;
  const int bm = t & 63;                   // 64 M tiles
  const int bn = t >> 6;                   // 6 N tiles
  const int r0 = bm * MT;
  const int n0 = bn * NT;
  const int tid = threadIdx.x;
  const int tx = tid & 15, ty = tid >> 4;  // 16x16 grid, 4x4 acc each

  __shared__ float As[KC][MT + 4];
  __shared__ float Bs[KC][NT + 4];

  float acc[4][4];
#pragma unroll
  for (int i = 0; i < 4; ++i)
#pragma unroll
    for (int j = 0; j < 4; ++j) acc[i][j] = 0.0f;

  const int kq = tid & 7,  mA = tid >> 3;  // A-stage (R9-verified)
  const int nq = tid & 15, kB = tid >> 4;  // B-stage

  const int c0base = kh * 128;
  for (int c0 = c0base; c0 < c0base + 128; c0 += KC) {
    const float4 a0 = *(const float4*)&ct[(size_t)(r0 + mA) * CC_ + c0 + kq * 4];
    const float4 a1 = *(const float4*)&ct[(size_t)(r0 + mA + 32) * CC_ + c0 + kq * 4];
    const float4 b0 = *(const float4*)&BT[(size_t)(c0 + kB) * NB2 + n0 + nq * 4];
    const float4 b1 = *(const float4*)&BT[(size_t)(c0 + kB + 16) * NB2 + n0 + nq * 4];
    __syncthreads();
    As[kq * 4 + 0][mA] = a0.x;
    As[kq * 4 + 1][mA] = a0.y;
    As[kq * 4 + 2][mA] = a0.z;
    As[kq * 4 + 3][mA] = a0.w;
    As[kq * 4 + 0][mA + 32] = a1.x;
    As[kq * 4 + 1][mA + 32] = a1.y;
    As[kq * 4 + 2][mA + 32] = a1.z;
    As[kq * 4 + 3][mA + 32] = a1.w;
    *(float4*)&Bs[kB][nq * 4]      = b0;
    *(float4*)&Bs[kB + 16][nq * 4] = b1;
    __syncthreads();
#pragma unroll
    for (int k = 0; k < KC; ++k) {
      const float4 av = *(const float4*)&As[k][ty * 4];
      const float4 bv = *(const float4*)&Bs[k][tx * 4];
      const float a[4] = {av.x, av.y, av.z, av.w};
      const float b[4] = {bv.x, bv.y, bv.z, bv.w};
#pragma unroll
      for (int i = 0; i < 4; ++i)
#pragma unroll
        for (int j = 0; j < 4; ++j) acc[i][j] = fmaf(a[i], b[j], acc[i][j]);
    }
  }

  float* Gh = G + (size_t)kh * HOFF;
#pragma unroll
  for (int i = 0; i < 4; ++i) {
    float4 o;
    o.x = acc[i][0]; o.y = acc[i][1]; o.z = acc[i][2]; o.w = acc[i][3];
    *(float4*)&Gh[(size_t)(r0 + ty * 4 + i) * NB2 + n0 + tx * 4] = o;
  }
}

// ---------------------------------------------------------------------------
// k_p: one thread per row; H[j] = G0 + G1 (split-K reduce folded in), then
// strict left-to-right j-sum. (p is continuous across trunc boundaries at
// output level — edge slot carries gauss(e^-2) * tiny attn weight — so the
// reordered accumulation is safe.)
// ---------------------------------------------------------------------------
__global__ __launch_bounds__(256) void k_p(const float* __restrict__ G,
    const float* __restrict__ Vp, float* __restrict__ p_out) {
  const int r = blockIdx.x * 256 + threadIdx.x;
  const float* h0 = G + (size_t)r * NB2 + CQ_;
  const float* h1 = G + HOFF + (size_t)r * NB2 + CQ_;
  float H[PS];
#pragma unroll
  for (int j = 0; j < PS; j += 4) {
    const float4 a = *(const float4*)&h0[j];
    const float4 b = *(const float4*)&h1[j];
    H[j + 0] = a.x + b.x; H[j + 1] = a.y + b.y;
    H[j + 2] = a.z + b.z; H[j + 3] = a.w + b.w;
  }
  float s = 0.0f;
#pragma unroll
  for (int j = 0; j < PS; ++j) s += Vp[j] * tanhf(H[j]);   // strict order
  p_out[r] = (float)S_LEN * (1.0f / (1.0f + expf(-s)));
}

// ---------------------------------------------------------------------------
// k_attn: R11's coalesced kernel with TWO changes:
//  (1) V = G0[row] + G1[row] summed in registers (split-K reduce, free);
//  (2) phase A processes 4 slots per iteration (16 float4 loads in flight
//      vs R11's 8) — R11 was latency-gapped (28us vs ~13us L2 floor) at the
//      grid-capped 16 waves/CU; doubling MLP halves the exposed latency.
// Phase B/C unchanged.
// ---------------------------------------------------------------------------
__global__ __launch_bounds__(256, 4) void k_attn(const float* __restrict__ q,
    const float* __restrict__ p_in, const float* __restrict__ G,
    float* __restrict__ out) {
  const int wid  = threadIdx.x >> 6;
  const int row  = (blockIdx.x << 2) + wid;
  const int lane = threadIdx.x & 63;
  const int b    = row >> 11;

  __shared__ float ss[4][128];   // scores (101..127 = -inf)
  __shared__ float sw[4][128];   // final weights

  const float p  = p_in[row];
  const float tp = truncf(p);
  const float* qb = q + (size_t)b * S_LEN * CQ_;

  const int sub = lane >> 4;          // window-slot within group
  const int sl  = lane & 15;          // subgroup lane
  const int c4  = sl * 4;             // coalesced float4 column offset

  const float* vr0 = G + (size_t)row * NB2;
  const float* vr1 = G + HOFF + (size_t)row * NB2;
  float4 v0, v1, v2, v3;
  {
    const float4 x0 = *(const float4*)(vr0 + c4);
    const float4 x1 = *(const float4*)(vr0 + 64 + c4);
    const float4 x2 = *(const float4*)(vr0 + 128 + c4);
    const float4 x3 = *(const float4*)(vr0 + 192 + c4);
    const float4 y0 = *(const float4*)(vr1 + c4);
    const float4 y1 = *(const float4*)(vr1 + 64 + c4);
    const float4 y2 = *(const float4*)(vr1 + 128 + c4);
    const float4 y3 = *(const float4*)(vr1 + 192 + c4);
    v0.x = x0.x + y0.x; v0.y = x0.y + y0.y; v0.z = x0.z + y0.z; v0.w = x0.w + y0.w;
    v1.x = x1.x + y1.x; v1.y = x1.y + y1.y; v1.z = x1.z + y1.z; v1.w = x1.w + y1.w;
    v2.x = x2.x + y2.x; v2.y = x2.y + y2.y; v2.z = x2.z + y2.z; v2.w = x2.w + y2.w;
    v3.x = x3.x + y3.x; v3.y = x3.y + y3.y; v3.z = x3.z + y3.z; v3.w = x3.w + y3.w;
  }

  if (lane >= KW - 64) ss[wid][64 + lane] = -INFINITY;   // slots 101..127

  for (int g = 0; g < 26; g += 4) {        // 7 iters; k<=111<128, ok-masked
    int   kk4[4];
    bool  ok4[4];
    float4 Q[4][4];
#pragma unroll
    for (int i = 0; i < 4; ++i) {
      const int k = ((g + i) << 2) + sub;            // uniform per subgroup
      const float t = p + (float)(k - DH) + 1.0f;    // ref op order
      const int raw = (int)t;                        // trunc toward zero
      const bool ok = (raw >= 1) && (raw <= S_LEN) && (k < KW);
      kk4[i] = k; ok4[i] = ok;
      const float* qr = qb + (size_t)(ok ? raw - 1 : 0) * CQ_;
      Q[i][0] = *(const float4*)(qr + c4);
      Q[i][1] = *(const float4*)(qr + 64 + c4);
      Q[i][2] = *(const float4*)(qr + 128 + c4);
      Q[i][3] = *(const float4*)(qr + 192 + c4);
    }
#pragma unroll
    for (int i = 0; i < 4; ++i) {
      float t0 = Q[i][0].x * v0.x, t1 = Q[i][1].x * v1.x;
      float t2 = Q[i][2].x * v2.x, t3 = Q[i][3].x * v3.x;
      t0 = fmaf(Q[i][0].y, v0.y, t0); t1 = fmaf(Q[i][1].y, v1.y, t1);
      t2 = fmaf(Q[i][2].y, v2.y, t2); t3 = fmaf(Q[i][3].y, v3.y, t3);
      t0 = fmaf(Q[i][0].z, v0.z, t0); t1 = fmaf(Q[i][1].z, v1.z, t1);
      t2 = fmaf(Q[i][2].z, v2.z, t2); t3 = fmaf(Q[i][3].z, v3.z, t3);
      t0 = fmaf(Q[i][0].w, v0.w, t0); t1 = fmaf(Q[i][1].w, v1.w, t1);
      t2 = fmaf(Q[i][2].w, v2.w, t2); t3 = fmaf(Q[i][3].w, v3.w, t3);
      float s = (t0 + t1) + (t2 + t3);
      s += __shfl_xor(s, 1, 64);
      s += __shfl_xor(s, 2, 64);
      s += __shfl_xor(s, 4, 64);
      s += __shfl_xor(s, 8, 64);
      s = ok4[i] ? s : -INFINITY;
      if (sl == 0) ss[wid][kk4[i]] = s;
    }
  }

  const float s0 = ss[wid][lane];
  const float s1 = ss[wid][64 + lane];

  float m = fmaxf(s0, s1);
#pragma unroll
  for (int off = 1; off < 64; off <<= 1) m = fmaxf(m, __shfl_xor(m, off, 64));

  const float e0 = __expf(s0 - m);                  // -inf -> 0
  const float e1 = __expf(s1 - m);
  float den = e0 + e1;
#pragma unroll
  for (int off = 1; off < 64; off <<= 1) den += __shfl_xor(den, off, 64);
  const float inv = 1.0f / den;

  float g0 = ((float)(lane - DH) + tp - p) / (float)DH;        // k = lane
  float g1 = ((float)(lane + (64 - DH)) + tp - p) / (float)DH; // k = 64+lane
  const float w0 = e0 * __expf(-2.0f * g0 * g0) * inv;
  const float w1 = e1 * __expf(-2.0f * g1 * g1) * inv;
  sw[wid][lane] = w0;
  if (lane < KW - 64) sw[wid][64 + lane] = w1;
  // wave-private LDS rows: intra-wave lgkmcnt ordering suffices

  // ---- Phase C: batch-4 survivor walk ----
  unsigned long long m0 = __ballot(w0 > WTH);
  unsigned long long m1 = __ballot((lane < KW - 64) && (w1 > WTH));

  float4 acc = make_float4(0.0f, 0.0f, 0.0f, 0.0f);
  while ((m0 | m1) != 0ull) {
    int kk[4];
#pragma unroll
    for (int i = 0; i < 4; ++i) {
      int k = -1;
      if (m0)      { k = __builtin_ctzll(m0);      m0 &= m0 - 1; }
      else if (m1) { k = 64 + __builtin_ctzll(m1); m1 &= m1 - 1; }
      kk[i] = k;
    }
#pragma unroll
    for (int i = 0; i < 4; ++i) {
      if (kk[i] >= 0) {                             // wave-uniform
        const float wk = sw[wid][kk[i]];
        const float t = p + (float)(kk[i] - DH) + 1.0f;
        const int r = (int)t - 1;                   // w>0 implies valid
        const float4 qv = *(const float4*)(qb + (size_t)r * CQ_ + lane * 4);
        acc.x = fmaf(wk, qv.x, acc.x);
        acc.y = fmaf(wk, qv.y, acc.y);
        acc.z = fmaf(wk, qv.z, acc.z);
        acc.w = fmaf(wk, qv.w, acc.w);
      }
    }
  }
  *(float4*)(out + (size_t)row * CQ_ + lane * 4) = acc;
}

// ---------------------------------------------------------------------------
extern "C" void kernel_launch(void* const* d_in, const int* in_sizes, int n_in,
                              void* d_out, int out_size, void* d_ws, size_t ws_size,
                              hipStream_t stream) {
  const float* q  = (const float*)d_in[0];
  const float* ct = (const float*)d_in[1];
  const float* Wa = (const float*)d_in[2];
  const float* Wp = (const float*)d_in[3];
  const float* Vp = (const float*)d_in[4];
  float* out = (float*)d_out;

  // ws (floats): p[4096] | BT[256*384] | G[2][4096*384]  (~13 MB of 268 MB)
  float* ws    = (float*)d_ws;
  float* p_ws  = ws;
  float* BT_ws = ws + NB * S_LEN;
  float* G_ws  = BT_ws + (size_t)CC_ * NB2;

  k_prep<<<CC_, NB2, 0, stream>>>(Wa, Wp, BT_ws);
  k_gemm<<<768, 256, 0, stream>>>(ct, BT_ws, G_ws);
  k_p   <<<(NB * S_LEN) / 256, 256, 0, stream>>>(G_ws, Vp, p_ws);
  k_attn<<<(NB * S_LEN) / 4, 256, 0, stream>>>(q, p_ws, G_ws, out);
}

// Round 13
// 111.276 us; speedup vs baseline: 1.0675x; 1.0675x over previous
//
#include <hip/hip_runtime.h>
#include <math.h>

#define S_LEN 2048
#define NB    2
#define CQ_   256
#define CC_   256
#define DH    50
#define KW    101
#define PS    100
#define RB    8     // rows per k_align block
#define HPAD  128   // zero-padded hidden width (branch-free loads)
#define WTH   1e-5f // phase-C weight skip threshold

// ---------------------------------------------------------------------------
// k_prep: WpT[c][j] = (j<100) ? Wp[j][c] : 0.   (exact R11 baseline)
// ---------------------------------------------------------------------------
__global__ __launch_bounds__(128) void k_prep(const float* __restrict__ Wp,
                                              float* __restrict__ WpT) {
  const int c = blockIdx.x, j = threadIdx.x;
  WpT[c * HPAD + j] = (j < PS) ? Wp[j * CC_ + c] : 0.0f;
}

// ---------------------------------------------------------------------------
// k_align: exact R11 baseline (36us measured; GEMM restructures lost 3x).
// ---------------------------------------------------------------------------
__global__ __launch_bounds__(384, 3) void k_align(const float* __restrict__ ct,
    const float* __restrict__ Wa, const float* __restrict__ WpT,
    const float* __restrict__ Vp, float* __restrict__ p_out,
    float* __restrict__ V_out) {
  const int r0  = blockIdx.x * RB;
  const int tid = threadIdx.x;
  const float* crow = ct + (size_t)r0 * CC_;   // uniform base

  __shared__ float red[RB][PS + 4];

  if (tid < CQ_) {
    const float* wa = Wa + tid;
    float acc[RB];
#pragma unroll
    for (int r = 0; r < RB; ++r) acc[r] = 0.0f;

    float4 cv0[RB], cv1[RB];
#pragma unroll
    for (int r = 0; r < RB; ++r) cv0[r] = *(const float4*)&crow[r * CC_];
    float w00 = wa[0 * CQ_], w01 = wa[1 * CQ_], w02 = wa[2 * CQ_], w03 = wa[3 * CQ_];

    for (int c = 0; c < CC_ - 4; c += 4) {
      const int cn = c + 4;
#pragma unroll
      for (int r = 0; r < RB; ++r) cv1[r] = *(const float4*)&crow[r * CC_ + cn];
      const float w10 = wa[(size_t)(cn + 0) * CQ_];
      const float w11 = wa[(size_t)(cn + 1) * CQ_];
      const float w12 = wa[(size_t)(cn + 2) * CQ_];
      const float w13 = wa[(size_t)(cn + 3) * CQ_];
#pragma unroll
      for (int r = 0; r < RB; ++r) {
        float t = acc[r];
        t = fmaf(cv0[r].x, w00, t);
        t = fmaf(cv0[r].y, w01, t);
        t = fmaf(cv0[r].z, w02, t);
        t = fmaf(cv0[r].w, w03, t);
        acc[r] = t;
      }
#pragma unroll
      for (int r = 0; r < RB; ++r) cv0[r] = cv1[r];
      w00 = w10; w01 = w11; w02 = w12; w03 = w13;
    }
#pragma unroll
    for (int r = 0; r < RB; ++r) {           // epilogue quad c=252
      float t = acc[r];
      t = fmaf(cv0[r].x, w00, t);
      t = fmaf(cv0[r].y, w01, t);
      t = fmaf(cv0[r].z, w02, t);
      t = fmaf(cv0[r].w, w03, t);
      acc[r] = t;
    }
#pragma unroll
    for (int r = 0; r < RB; ++r)
      V_out[(size_t)(r0 + r) * CQ_ + tid] = acc[r];
  } else {
    const int j = tid - CQ_;
    const float* wh = WpT + j;
    float ah[RB];
#pragma unroll
    for (int r = 0; r < RB; ++r) ah[r] = 0.0f;

    float4 cv0[RB], cv1[RB];
#pragma unroll
    for (int r = 0; r < RB; ++r) cv0[r] = *(const float4*)&crow[r * CC_];
    float w00 = wh[0 * HPAD], w01 = wh[1 * HPAD], w02 = wh[2 * HPAD], w03 = wh[3 * HPAD];

    for (int c = 0; c < CC_ - 4; c += 4) {
      const int cn = c + 4;
#pragma unroll
      for (int r = 0; r < RB; ++r) cv1[r] = *(const float4*)&crow[r * CC_ + cn];
      const float w10 = wh[(size_t)(cn + 0) * HPAD];
      const float w11 = wh[(size_t)(cn + 1) * HPAD];
      const float w12 = wh[(size_t)(cn + 2) * HPAD];
      const float w13 = wh[(size_t)(cn + 3) * HPAD];
#pragma unroll
      for (int r = 0; r < RB; ++r) {
        float t = ah[r];                     // fmaf order x,y,z,w == R2..R11
        t = fmaf(cv0[r].x, w00, t);
        t = fmaf(cv0[r].y, w01, t);
        t = fmaf(cv0[r].z, w02, t);
        t = fmaf(cv0[r].w, w03, t);
        ah[r] = t;
      }
#pragma unroll
      for (int r = 0; r < RB; ++r) cv0[r] = cv1[r];
      w00 = w10; w01 = w11; w02 = w12; w03 = w13;
    }
#pragma unroll
    for (int r = 0; r < RB; ++r) {           // epilogue quad c=252
      float t = ah[r];
      t = fmaf(cv0[r].x, w00, t);
      t = fmaf(cv0[r].y, w01, t);
      t = fmaf(cv0[r].z, w02, t);
      t = fmaf(cv0[r].w, w03, t);
      ah[r] = t;
    }
    if (j < PS) {
      const float vp = Vp[j];
#pragma unroll
      for (int r = 0; r < RB; ++r) red[r][j] = vp * tanhf(ah[r]);
    }
  }
  __syncthreads();
  if (tid < RB) {                         // serial j-sum: identical to R2..R11
    float s = 0.0f;
    for (int j = 0; j < PS; ++j) s += red[tid][j];
    p_out[r0 + tid] = (float)S_LEN * (1.0f / (1.0f + expf(-s)));
  }
}

// ---------------------------------------------------------------------------
// k_attn: R11's coalesced kernel, ONE change — TWO WAVES PER ROW.
// Block = 256 thr = 2 rows x 2 waves; wave `half` handles groups
// 13*half..13*half+12 (R11 pair structure kept; overlap/overflow groups are
// ok-masked or write identical values — benign). Grid 2048 blocks,
// launch_bounds(256,8) -> 32 waves/CU (R11 was grid-capped at 16; phase A
// is latency-bound so TLP x2 should halve exposed latency).
// Softmax redundant per wave (identical fp). Phase C: survivors split by
// parity between the row's 2 waves; partials via LDS + barrier.
// V aliases out (block reads only its 2 rows, writes them after barriers).
// ---------------------------------------------------------------------------
__global__ __launch_bounds__(256, 8) void k_attn(const float* __restrict__ q,
    const float* __restrict__ p_in, const float* V,   // aliases out
    float* out) {
  const int tid  = threadIdx.x;
  const int wid  = tid >> 6;
  const int rloc = wid >> 1;                // local row 0/1
  const int half = wid & 1;                 // group-range half
  const int row  = (blockIdx.x << 1) + rloc;
  const int lane = tid & 63;
  const int b    = row >> 11;

  __shared__ float ss[2][128];   // scores per local row (101..127 = -inf)
  __shared__ float sw[2][128];   // weights per local row
  __shared__ float sacc[4][CQ_]; // per-wave phase-C partials

  const float p  = p_in[row];
  const float tp = truncf(p);
  const float* qb = q + (size_t)b * S_LEN * CQ_;

  const int sub = lane >> 4;          // window-slot within group
  const int sl  = lane & 15;          // subgroup lane
  const int c4  = sl * 4;             // coalesced float4 column offset

  const float* vrow = V + (size_t)row * CQ_;
  const float4 v0 = *(const float4*)(vrow + c4);        // cols   0..63
  const float4 v1 = *(const float4*)(vrow + 64 + c4);   // cols  64..127
  const float4 v2 = *(const float4*)(vrow + 128 + c4);  // cols 128..191
  const float4 v3 = *(const float4*)(vrow + 192 + c4);  // cols 192..255

  if (lane >= KW - 64) ss[rloc][64 + lane] = -INFINITY;  // slots 101..127

  for (int gg = 0; gg < 13; gg += 2) {
    const int ga = half * 13 + gg;                 // groups for this wave
    const int ka = (ga << 2) + sub;                // uniform per 16-subgroup
    const int kb = ka + 4;                         // group ga+1 (<=26, masked)
    const float ta = p + (float)(ka - DH) + 1.0f;  // ref op order
    const float tb = p + (float)(kb - DH) + 1.0f;
    const int rawa = (int)ta;                      // trunc toward zero
    const int rawb = (int)tb;
    const bool oka = (rawa >= 1) && (rawa <= S_LEN) && (ka < KW);
    const bool okb = (rawb >= 1) && (rawb <= S_LEN) && (kb < KW);
    const float* qra = qb + (size_t)(oka ? rawa - 1 : 0) * CQ_;
    const float* qrb = qb + (size_t)(okb ? rawb - 1 : 0) * CQ_;

    // 8 loads in flight; each instr: 4 rows x 256B contiguous
    const float4 a0 = *(const float4*)(qra + c4);
    const float4 a1 = *(const float4*)(qra + 64 + c4);
    const float4 a2 = *(const float4*)(qra + 128 + c4);
    const float4 a3 = *(const float4*)(qra + 192 + c4);
    const float4 b0 = *(const float4*)(qrb + c4);
    const float4 b1 = *(const float4*)(qrb + 64 + c4);
    const float4 b2 = *(const float4*)(qrb + 128 + c4);
    const float4 b3 = *(const float4*)(qrb + 192 + c4);

    float t0 = a0.x * v0.x, t1 = a1.x * v1.x, t2 = a2.x * v2.x, t3 = a3.x * v3.x;
    t0 = fmaf(a0.y, v0.y, t0); t1 = fmaf(a1.y, v1.y, t1);
    t2 = fmaf(a2.y, v2.y, t2); t3 = fmaf(a3.y, v3.y, t3);
    t0 = fmaf(a0.z, v0.z, t0); t1 = fmaf(a1.z, v1.z, t1);
    t2 = fmaf(a2.z, v2.z, t2); t3 = fmaf(a3.z, v3.z, t3);
    t0 = fmaf(a0.w, v0.w, t0); t1 = fmaf(a1.w, v1.w, t1);
    t2 = fmaf(a2.w, v2.w, t2); t3 = fmaf(a3.w, v3.w, t3);
    float sA = (t0 + t1) + (t2 + t3);
    sA += __shfl_xor(sA, 1, 64);
    sA += __shfl_xor(sA, 2, 64);
    sA += __shfl_xor(sA, 4, 64);
    sA += __shfl_xor(sA, 8, 64);
    sA = oka ? sA : -INFINITY;
    if (sl == 0 && ka < 128) ss[rloc][ka] = sA;

    float u0 = b0.x * v0.x, u1 = b1.x * v1.x, u2 = b2.x * v2.x, u3 = b3.x * v3.x;
    u0 = fmaf(b0.y, v0.y, u0); u1 = fmaf(b1.y, v1.y, u1);
    u2 = fmaf(b2.y, v2.y, u2); u3 = fmaf(b3.y, v3.y, u3);
    u0 = fmaf(b0.z, v0.z, u0); u1 = fmaf(b1.z, v1.z, u1);
    u2 = fmaf(b2.z, v2.z, u2); u3 = fmaf(b3.z, v3.z, u3);
    u0 = fmaf(b0.w, v0.w, u0); u1 = fmaf(b1.w, v1.w, u1);
    u2 = fmaf(b2.w, v2.w, u2); u3 = fmaf(b3.w, v3.w, u3);
    float sB = (u0 + u1) + (u2 + u3);
    sB += __shfl_xor(sB, 1, 64);
    sB += __shfl_xor(sB, 2, 64);
    sB += __shfl_xor(sB, 4, 64);
    sB += __shfl_xor(sB, 8, 64);
    sB = okb ? sB : -INFINITY;
    if (sl == 0 && kb < 128) ss[rloc][kb] = sB;
  }
  __syncthreads();

  // ---- Phase B: redundant per wave (identical fp results per row) ----
  const float s0 = ss[rloc][lane];
  const float s1 = ss[rloc][64 + lane];

  float m = fmaxf(s0, s1);
#pragma unroll
  for (int off = 1; off < 64; off <<= 1) m = fmaxf(m, __shfl_xor(m, off, 64));

  const float e0 = __expf(s0 - m);                  // -inf -> 0
  const float e1 = __expf(s1 - m);
  float den = e0 + e1;
#pragma unroll
  for (int off = 1; off < 64; off <<= 1) den += __shfl_xor(den, off, 64);
  const float inv = 1.0f / den;

  float g0 = ((float)(lane - DH) + tp - p) / (float)DH;        // k = lane
  float g1 = ((float)(lane + (64 - DH)) + tp - p) / (float)DH; // k = 64+lane
  const float w0 = e0 * __expf(-2.0f * g0 * g0) * inv;
  const float w1 = e1 * __expf(-2.0f * g1 * g1) * inv;
  sw[rloc][lane] = w0;                              // dup write same value
  if (lane < KW - 64) sw[rloc][64 + lane] = w1;

  // ---- Phase C: survivors split by parity between the row's 2 waves ----
  unsigned long long m0 = __ballot(w0 > WTH);
  unsigned long long m1 = __ballot((lane < KW - 64) && (w1 > WTH));

  float4 acc = make_float4(0.0f, 0.0f, 0.0f, 0.0f);
  int cnt = 0;
  while ((m0 | m1) != 0ull) {
    int kk[4];
#pragma unroll
    for (int i = 0; i < 4; ++i) {
      int k = -1;
      if (m0)      { k = __builtin_ctzll(m0);      m0 &= m0 - 1; }
      else if (m1) { k = 64 + __builtin_ctzll(m1); m1 &= m1 - 1; }
      kk[i] = k;
    }
#pragma unroll
    for (int i = 0; i < 4; ++i) {
      if (kk[i] >= 0) {                             // wave-uniform
        if ((cnt & 1) == half) {                    // this wave's share
          const float wk = sw[rloc][kk[i]];
          const float t = p + (float)(kk[i] - DH) + 1.0f;
          const int r = (int)t - 1;                 // w>0 implies valid
          const float4 qv = *(const float4*)(qb + (size_t)r * CQ_ + lane * 4);
          acc.x = fmaf(wk, qv.x, acc.x);
          acc.y = fmaf(wk, qv.y, acc.y);
          acc.z = fmaf(wk, qv.z, acc.z);
          acc.w = fmaf(wk, qv.w, acc.w);
        }
        ++cnt;
      }
    }
  }
  *(float4*)&sacc[wid][lane * 4] = acc;
  __syncthreads();

  const int row0 = (blockIdx.x << 1);
  out[(size_t)row0 * CQ_ + tid]       = sacc[0][tid] + sacc[1][tid];
  out[(size_t)(row0 + 1) * CQ_ + tid] = sacc[2][tid] + sacc[3][tid];
}

// ---------------------------------------------------------------------------
extern "C" void kernel_launch(void* const* d_in, const int* in_sizes, int n_in,
                              void* d_out, int out_size, void* d_ws, size_t ws_size,
                              hipStream_t stream) {
  const float* q  = (const float*)d_in[0];
  const float* ct = (const float*)d_in[1];
  const float* Wa = (const float*)d_in[2];
  const float* Wp = (const float*)d_in[3];
  const float* Vp = (const float*)d_in[4];
  float* out = (float*)d_out;

  // ws (floats): p[4096] | WpT[256*128]  -> 147 KB
  float* ws     = (float*)d_ws;
  float* p_ws   = ws;
  float* WpT_ws = ws + NB * S_LEN;

  k_prep <<<CC_, HPAD, 0, stream>>>(Wp, WpT_ws);
  k_align<<<(NB * S_LEN) / RB, 384, 0, stream>>>(ct, Wa, WpT_ws, Vp, p_ws, out);
  k_attn <<<(NB * S_LEN) / 2, 256, 0, stream>>>(q, p_ws, out, out);
}